// Round 3
// baseline (106.817 us; speedup 1.0000x reference)
//
#include <hip/hip_runtime.h>

// CIN (xDeepFM) fused kernel for MI355X (gfx950), bf16 MFMA path, round 3.
// L0: M=256 K=1600 (50 steps of 32), B-frags (z) computed IN-REGISTER per wave
//     from read-only xs -> zero barriers in the K-loop.
// L1: reassociated out1[o,c] = sum_m x[m,c]*(W1_m @ h)[o,c]; h persistent in VGPRs.
// Weights stream from global (L2-resident), 2-deep register double-buffer.
// Only 2 __syncthreads() in the whole kernel.

typedef __bf16 bf16x8 __attribute__((ext_vector_type(8)));
typedef float f32x4 __attribute__((ext_vector_type(4)));

#define NB 2
#define NBLK 512
#define THREADS 256
#define K0STEPS 50   // 50*32 = 1600; rows with m==39 are zero-padded

__global__ __launch_bounds__(256) void prep_kernel(
    const float* __restrict__ w0, const float* __restrict__ w1,
    __bf16* __restrict__ w0b, __bf16* __restrict__ w1p) {
  int stride = gridDim.x * blockDim.x;
  int tid = blockIdx.x * blockDim.x + threadIdx.x;
  // w0b[blk][o][j]: K reordered as i' = m*40 + n (n<39 valid, else 0); i'>=1560 -> 0
  const int n0 = K0STEPS * 256 * 32;
  for (int idx = tid; idx < n0; idx += stride) {
    int j = idx & 31, o = (idx >> 5) & 255, blk = idx >> 13;
    int ip = blk * 32 + j;
    float v = 0.f;
    if (ip < 1560) {
      unsigned m = (unsigned)ip / 40u;
      unsigned n = (unsigned)ip - m * 40u;
      if (n < 39u) v = w0[o * 1521 + m * 39 + n];
    }
    w0b[idx] = (__bf16)v;
  }
  // w1p[((m*4+ks)*128 + o)*32 + j] = w1[o][m*128 + ks*32 + j]
  const int n1 = 39 * 4 * 128 * 32;
  for (int idx = tid; idx < n1; idx += stride) {
    int j = idx & 31, o = (idx >> 5) & 127, q = idx >> 12;
    int ks = q & 3, m = q >> 2;
    w1p[idx] = (__bf16)w1[o * 4992 + m * 128 + ks * 32 + j];
  }
}

__global__ __launch_bounds__(256, 2) void cin_kernel(
    const float* __restrict__ x,
    const __bf16* __restrict__ w0b, const float* __restrict__ b0,
    const __bf16* __restrict__ w1p, const float* __restrict__ b1,
    float* __restrict__ out) {
  // LDS: 5120 + 17408 = 22528 B (read-only after the two fill points)
  __shared__ __align__(16) __bf16 xs[NB * 32 * 40];    // [c=(b,d)][40] (m=39 slot zero)
  __shared__ __align__(16) __bf16 h1[NB * 32 * 136];   // [c][136] h1a (bf16)

  const int t = threadIdx.x;
  const int bb = blockIdx.x * NB;
  const int w = t >> 6;          // wave id
  const int l15 = t & 15;
  const int lhi = (t >> 4) & 3;

  // ---- load x[b] -> xs transposed [c][m], bf16 ----
  for (int idx = t; idx < NB * 39 * 32; idx += THREADS) {
    int b = idx / 1248; int rem = idx - b * 1248;
    int m = rem >> 5; int d = rem & 31;
    xs[(b * 32 + d) * 40 + m] = (__bf16)x[(bb + b) * 1248 + rem];
  }
  if (t < NB * 32) xs[t * 40 + 39] = (__bf16)0.f;  // zero the m=39 pad
  __syncthreads();

  // ================= LAYER 0 (barrier-free K-loop) =================
  f32x4 acc[4][4] = {};

  auto loadA0 = [&](int s, bf16x8 (&af)[4]) {
#pragma unroll
    for (int mt = 0; mt < 4; ++mt) {
      int o = w * 64 + mt * 16 + l15;
      af[mt] = *(const bf16x8*)(w0b + s * 8192 + o * 32 + lhi * 8);
    }
  };
  // per-wave in-register B fragments: bz[nt] holds z[k=i0..i0+7][c=nt*16+l15]
  auto zfr = [&](int s, bf16x8 (&bz)[4]) {
    unsigned i0 = (unsigned)(s * 32) + (unsigned)lhi * 8u;
    unsigned m = (i0 * 52429u) >> 21;   // i0/40 (exact for i0 < 2^16)
    unsigned nb = i0 - m * 40u;
#pragma unroll
    for (int nt = 0; nt < 4; ++nt) {
      int c = nt * 16 + l15;
      float xm = (float)xs[c * 40 + m];             // m==39 -> 0
      bf16x8 xn = *(const bf16x8*)&xs[c * 40 + nb]; // 16B-aligned (80B rows, nb*2 % 16 == 0)
      bf16x8 vz;
#pragma unroll
      for (int j = 0; j < 8; ++j) vz[j] = (__bf16)(xm * (float)xn[j]);
      bz[nt] = vz;
    }
  };
  auto comp0 = [&](bf16x8 (&af)[4], bf16x8 (&bz)[4]) {
#pragma unroll
    for (int mt = 0; mt < 4; ++mt)
#pragma unroll
      for (int nt = 0; nt < 4; ++nt)
        acc[mt][nt] = __builtin_amdgcn_mfma_f32_16x16x32_bf16(af[mt], bz[nt], acc[mt][nt], 0, 0, 0);
  };

  bf16x8 afA[4], afB[4];
  loadA0(0, afA);
  loadA0(1, afB);
  for (int s = 0; s < K0STEPS; s += 2) {
    bf16x8 bzA[4], bzB[4];
    zfr(s, bzA);
    comp0(afA, bzA);
    if (s + 2 < K0STEPS) loadA0(s + 2, afA);
    zfr(s + 1, bzB);
    comp0(afB, bzB);
    if (s + 3 < K0STEPS) loadA0(s + 3, afB);
  }

  // ---- epilogue 0: bias+relu; o<128 -> h1a LDS; o>=128 -> d-sum -> out[ch 0..127]
  if (w < 2) {
#pragma unroll
    for (int mt = 0; mt < 4; ++mt) {
#pragma unroll
      for (int nt = 0; nt < 4; ++nt) {
        int c = nt * 16 + l15;
        int hbase = c * 136;
#pragma unroll
        for (int r = 0; r < 4; ++r) {
          int o = w * 64 + mt * 16 + lhi * 4 + r;
          float v = fmaxf(acc[mt][nt][r] + b0[o], 0.f);
          h1[hbase + o] = (__bf16)v;
        }
      }
    }
  } else {
#pragma unroll
    for (int mt = 0; mt < 4; ++mt) {
#pragma unroll
      for (int r = 0; r < 4; ++r) {
        int o = w * 64 + mt * 16 + lhi * 4 + r;  // 128..255
        float bias = b0[o];
        float sb0 = 0.f, sb1 = 0.f;
#pragma unroll
        for (int nt = 0; nt < 4; ++nt) {
          float v = fmaxf(acc[mt][nt][r] + bias, 0.f);
          v += __shfl_xor(v, 1); v += __shfl_xor(v, 2);
          v += __shfl_xor(v, 4); v += __shfl_xor(v, 8);
          if (nt < 2) sb0 += v; else sb1 += v;
        }
        if (l15 == 0) {
          out[(bb + 0) * 256 + (o - 128)] = sb0;
          out[(bb + 1) * 256 + (o - 128)] = sb1;
        }
      }
    }
  }
  __syncthreads();  // h1a visible to all waves

  // ================= LAYER 1 (reassociated, barrier-free) =================
  // hf[ks][nt]: persistent B fragments of h (128 x 64), 64 VGPRs
  bf16x8 hf[4][4];
#pragma unroll
  for (int ks = 0; ks < 4; ++ks)
#pragma unroll
    for (int nt = 0; nt < 4; ++nt)
      hf[ks][nt] = *(const bf16x8*)&h1[(nt * 16 + l15) * 136 + ks * 32 + lhi * 8];

  f32x4 acc2[2][4] = {};

  auto loadA1 = [&](int m, bf16x8 (&wf)[4][2]) {
#pragma unroll
    for (int ks = 0; ks < 4; ++ks)
#pragma unroll
      for (int mt = 0; mt < 2; ++mt) {
        int o = w * 32 + mt * 16 + l15;
        wf[ks][mt] = *(const bf16x8*)(w1p + ((m * 4 + ks) * 128 + o) * 32 + lhi * 8);
      }
  };
  auto computeM = [&](int m, bf16x8 (&wf)[4][2]) {
    float xmv[4];
#pragma unroll
    for (int nt = 0; nt < 4; ++nt) xmv[nt] = (float)xs[(nt * 16 + l15) * 40 + m];
    f32x4 Y[2][4];
#pragma unroll
    for (int ks = 0; ks < 4; ++ks)
#pragma unroll
      for (int mt = 0; mt < 2; ++mt)
#pragma unroll
        for (int nt = 0; nt < 4; ++nt) {
          f32x4 cin = (ks == 0) ? (f32x4){0.f, 0.f, 0.f, 0.f} : Y[mt][nt];
          Y[mt][nt] = __builtin_amdgcn_mfma_f32_16x16x32_bf16(wf[ks][mt], hf[ks][nt], cin, 0, 0, 0);
        }
#pragma unroll
    for (int mt = 0; mt < 2; ++mt)
#pragma unroll
      for (int nt = 0; nt < 4; ++nt)
#pragma unroll
        for (int r = 0; r < 4; ++r)
          acc2[mt][nt][r] += xmv[nt] * Y[mt][nt][r];
  };

  bf16x8 wfA[4][2], wfB[4][2];
  loadA1(0, wfA);
  loadA1(1, wfB);
  for (int m = 0; m < 38; m += 2) {
    computeM(m, wfA);
    if (m + 2 < 39) loadA1(m + 2, wfA);
    computeM(m + 1, wfB);
    if (m + 3 < 39) loadA1(m + 3, wfB);
  }
  computeM(38, wfA);

  // ---- epilogue 1: bias+relu, d-sum -> out[ch 128..255]
#pragma unroll
  for (int mt = 0; mt < 2; ++mt) {
#pragma unroll
    for (int r = 0; r < 4; ++r) {
      int o = w * 32 + mt * 16 + lhi * 4 + r;  // 0..127
      float bias = b1[o];
      float sb0 = 0.f, sb1 = 0.f;
#pragma unroll
      for (int nt = 0; nt < 4; ++nt) {
        float v = fmaxf(acc2[mt][nt][r] + bias, 0.f);
        v += __shfl_xor(v, 1); v += __shfl_xor(v, 2);
        v += __shfl_xor(v, 4); v += __shfl_xor(v, 8);
        if (nt < 2) sb0 += v; else sb1 += v;
      }
      if (l15 == 0) {
        out[(bb + 0) * 256 + 128 + o] = sb0;
        out[(bb + 1) * 256 + 128 + o] = sb1;
      }
    }
  }
}

extern "C" void kernel_launch(void* const* d_in, const int* in_sizes, int n_in,
                              void* d_out, int out_size, void* d_ws, size_t ws_size,
                              hipStream_t stream) {
  const float* x  = (const float*)d_in[0];
  const float* w0 = (const float*)d_in[1];
  const float* b0 = (const float*)d_in[2];
  const float* w1 = (const float*)d_in[3];
  const float* b1 = (const float*)d_in[4];
  float* out = (float*)d_out;

  __bf16* w0b = (__bf16*)d_ws;                 // 50*256*32 bf16 = 819200 B
  __bf16* w1p = w0b + K0STEPS * 256 * 32;      // 39*4*128*32 bf16 = 1277952 B

  prep_kernel<<<256, 256, 0, stream>>>(w0, w1, w0b, w1p);
  cin_kernel<<<NBLK, THREADS, 0, stream>>>(x, w0b, b0, w1p, b1, out);
}